// Round 1
// baseline (1462.636 us; speedup 1.0000x reference)
//
#include <hip/hip_runtime.h>

#define THREADS 256

__global__ void deg_kernel(const int* __restrict__ row, float* __restrict__ deg, int E) {
    int e = blockIdx.x * blockDim.x + threadIdx.x;
    if (e < E) atomicAdd(&deg[row[e]], 1.0f);
}

__global__ void dinv_kernel(float* __restrict__ deg, int N) {
    int i = blockIdx.x * blockDim.x + threadIdx.x;
    if (i < N) {
        float d = deg[i];
        deg[i] = d > 0.f ? rsqrtf(d) : 0.f;
    }
}

// out is [N][128] f32 = [N][32] float4; x is [N][64] f32 = [N][16] float4.
// First 16 float4 of each out row = x row; last 16 zeroed (accumulator).
__global__ void init_out_kernel(const float4* __restrict__ x, float4* __restrict__ out, int total) {
    int i = blockIdx.x * blockDim.x + threadIdx.x;  // over N*32
    if (i >= total) return;
    int n = i >> 5, c = i & 31;
    float4 z = {0.f, 0.f, 0.f, 0.f};
    out[i] = (c < 16) ? x[n * 16 + c] : z;
}

// 16 threads per edge: each loads one float4 of x[col] and atomically adds
// norm*v into out[row, 64 + lane*4 .. +3].
__global__ void scatter_kernel(const int* __restrict__ row, const int* __restrict__ col,
                               const float* __restrict__ dinv,
                               const float4* __restrict__ x,
                               float* __restrict__ out, int E) {
    int t = blockIdx.x * blockDim.x + threadIdx.x;
    int e = t >> 4;
    if (e >= E) return;
    int lane = t & 15;
    int r = row[e], c = col[e];
    float norm = dinv[r] * dinv[c];
    float4 v = x[(size_t)c * 16 + lane];
    float* o = out + (size_t)r * 128 + 64 + lane * 4;
    atomicAdd(o + 0, norm * v.x);
    atomicAdd(o + 1, norm * v.y);
    atomicAdd(o + 2, norm * v.z);
    atomicAdd(o + 3, norm * v.w);
}

extern "C" void kernel_launch(void* const* d_in, const int* in_sizes, int n_in,
                              void* d_out, int out_size, void* d_ws, size_t ws_size,
                              hipStream_t stream) {
    const float* x = (const float*)d_in[0];
    const int* ei = (const int*)d_in[1];

    const int N = in_sizes[0] / 64;       // 100000
    const int E = in_sizes[1] / 2;        // 1600000
    const int* row = ei;
    const int* col = ei + E;

    float* dinv = (float*)d_ws;           // N floats
    float* out = (float*)d_out;           // N * 128 floats

    // 1) zero degree accumulator
    hipMemsetAsync(dinv, 0, (size_t)N * sizeof(float), stream);

    // 2) degree histogram
    deg_kernel<<<(E + THREADS - 1) / THREADS, THREADS, 0, stream>>>(row, dinv, E);

    // 3) dinv = deg>0 ? rsqrt(deg) : 0
    dinv_kernel<<<(N + THREADS - 1) / THREADS, THREADS, 0, stream>>>(dinv, N);

    // 4) init out: copy x into [:, :64], zero [:, 64:]
    int total = N * 32;
    init_out_kernel<<<(total + THREADS - 1) / THREADS, THREADS, 0, stream>>>(
        (const float4*)x, (float4*)out, total);

    // 5) edge scatter with atomics (16 threads per edge)
    long long st = (long long)E * 16;
    int blocks = (int)((st + THREADS - 1) / THREADS);
    scatter_kernel<<<blocks, THREADS, 0, stream>>>(row, col, dinv, (const float4*)x, out, E);
}

// Round 2
// 518.467 us; speedup vs baseline: 2.8211x; 2.8211x over previous
//
#include <hip/hip_runtime.h>

#define THREADS 256

__global__ void deg_kernel(const int* __restrict__ row, int* __restrict__ deg, int E) {
    int e = blockIdx.x * blockDim.x + threadIdx.x;
    if (e < E) atomicAdd(&deg[row[e]], 1);
}

// Single-block hierarchical exclusive scan of deg -> row_start & cursor; also dinv.
__global__ __launch_bounds__(1024) void scan_kernel(const int* __restrict__ deg,
                                                    int* __restrict__ row_start,
                                                    int* __restrict__ cursor,
                                                    float* __restrict__ dinv, int N) {
    __shared__ int wsum[16];
    __shared__ int wexcl[16];
    __shared__ int total_s;
    const int K = 8;
    const int CHUNK = 1024 * K;  // 8192 elems per pass
    int lane = threadIdx.x & 63;
    int wid = threadIdx.x >> 6;
    int carry = 0;
    for (int base = 0; base < N; base += CHUNK) {
        int idx = base + threadIdx.x * K;
        int v[K];
        int lsum = 0;
#pragma unroll
        for (int k = 0; k < K; ++k) {
            v[k] = (idx + k < N) ? deg[idx + k] : 0;
            lsum += v[k];
        }
        // wave-inclusive scan of per-thread sums
        int ls = lsum;
#pragma unroll
        for (int off = 1; off < 64; off <<= 1) {
            int t = __shfl_up(ls, off, 64);
            if (lane >= off) ls += t;
        }
        if (lane == 63) wsum[wid] = ls;
        __syncthreads();
        if (wid == 0 && lane < 16) {
            int s = wsum[lane];
            int ss = s;
#pragma unroll
            for (int off = 1; off < 16; off <<= 1) {
                int t = __shfl_up(ss, off, 64);
                if (lane >= off) ss += t;
            }
            wexcl[lane] = ss - s;
            if (lane == 15) total_s = ss;
        }
        __syncthreads();
        int run = carry + wexcl[wid] + (ls - lsum);
#pragma unroll
        for (int k = 0; k < K; ++k) {
            int i = idx + k;
            if (i < N) {
                row_start[i] = run;
                cursor[i] = run;
                dinv[i] = (v[k] > 0) ? rsqrtf((float)v[k]) : 0.f;
            }
            run += v[k];
        }
        carry += total_s;
        __syncthreads();  // protect wsum/wexcl before next pass
    }
}

__global__ void build_csr(const int* __restrict__ row, const int* __restrict__ col,
                          int* __restrict__ cursor, int* __restrict__ csr_col, int E) {
    int e = blockIdx.x * blockDim.x + threadIdx.x;
    if (e >= E) return;
    int r = row[e];
    int pos = atomicAdd(&cursor[r], 1);
    csr_col[pos] = col[e];
}

// One wave (64 lanes) per node; lane == feature. After build_csr,
// cursor[i] == row_start[i] + deg[i], i.e. the row end.
__global__ void aggregate(const float* __restrict__ x,
                          const int* __restrict__ row_start,
                          const int* __restrict__ row_end,
                          const int* __restrict__ csr_col,
                          const float* __restrict__ dinv,
                          float* __restrict__ out, int N) {
    int node = blockIdx.x * (blockDim.x >> 6) + (threadIdx.x >> 6);
    int d = threadIdx.x & 63;
    if (node >= N) return;
    int s = row_start[node];
    int e = row_end[node];
    float acc = 0.f;
    for (int i = s; i < e; ++i) {
        int c = csr_col[i];  // wave-uniform
        acc += dinv[c] * x[(size_t)c * 64 + d];
    }
    out[(size_t)node * 128 + d] = x[(size_t)node * 64 + d];
    out[(size_t)node * 128 + 64 + d] = dinv[node] * acc;
}

extern "C" void kernel_launch(void* const* d_in, const int* in_sizes, int n_in,
                              void* d_out, int out_size, void* d_ws, size_t ws_size,
                              hipStream_t stream) {
    const float* x = (const float*)d_in[0];
    const int* ei = (const int*)d_in[1];

    const int N = in_sizes[0] / 64;   // 100000
    const int E = in_sizes[1] / 2;    // 1600000
    const int* row = ei;
    const int* col = ei + E;

    // workspace layout (16B-aligned slabs)
    char* ws = (char*)d_ws;
    int* deg       = (int*)ws;                 ws += (size_t)N * sizeof(int);
    int* row_start = (int*)ws;                 ws += (size_t)N * sizeof(int);
    int* cursor    = (int*)ws;                 ws += (size_t)N * sizeof(int);
    float* dinv    = (float*)ws;               ws += (size_t)N * sizeof(float);
    int* csr_col   = (int*)ws;                 // E ints

    float* out = (float*)d_out;

    hipMemsetAsync(deg, 0, (size_t)N * sizeof(int), stream);

    deg_kernel<<<(E + THREADS - 1) / THREADS, THREADS, 0, stream>>>(row, deg, E);

    scan_kernel<<<1, 1024, 0, stream>>>(deg, row_start, cursor, dinv, N);

    build_csr<<<(E + THREADS - 1) / THREADS, THREADS, 0, stream>>>(row, col, cursor, csr_col, E);

    // 4 nodes per 256-thread block (one wave each)
    int nodes_per_block = THREADS / 64;
    int blocks = (N + nodes_per_block - 1) / nodes_per_block;
    aggregate<<<blocks, THREADS, 0, stream>>>(x, row_start, cursor, csr_col, dinv, out, N);
}

// Round 3
// 283.499 us; speedup vs baseline: 5.1592x; 1.8288x over previous
//
#include <hip/hip_runtime.h>

#define THREADS 256
#define SCAN_K 8
#define SCAN_CHUNK (THREADS * SCAN_K)  // 2048 elements per block
#define NWAVES (THREADS / 64)

__global__ void deg_kernel(const int* __restrict__ row, int* __restrict__ deg, int E) {
    int e = blockIdx.x * blockDim.x + threadIdx.x;
    if (e < E) atomicAdd(&deg[row[e]], 1);
}

// Pass A: per-block sum of a 2048-element chunk of deg.
__global__ void scan_sums(const int* __restrict__ deg, int* __restrict__ partials, int N) {
    __shared__ int wsum[NWAVES];
    int idx = blockIdx.x * SCAN_CHUNK + threadIdx.x * SCAN_K;
    int lsum = 0;
#pragma unroll
    for (int k = 0; k < SCAN_K; ++k)
        lsum += (idx + k < N) ? deg[idx + k] : 0;
#pragma unroll
    for (int off = 32; off >= 1; off >>= 1)
        lsum += __shfl_xor(lsum, off, 64);
    int lane = threadIdx.x & 63, wid = threadIdx.x >> 6;
    if (lane == 0) wsum[wid] = lsum;
    __syncthreads();
    if (threadIdx.x == 0) {
        int s = 0;
#pragma unroll
        for (int w = 0; w < NWAVES; ++w) s += wsum[w];
        partials[blockIdx.x] = s;
    }
}

// Pass B: exclusive scan of per-block partials (single wave, loops if nb > 64).
__global__ void scan_partials(int* __restrict__ partials, int nb) {
    int lane = threadIdx.x;  // 64 threads
    int carry = 0;
    for (int base = 0; base < nb; base += 64) {
        int i = base + lane;
        int v = (i < nb) ? partials[i] : 0;
        int s = v;
#pragma unroll
        for (int off = 1; off < 64; off <<= 1) {
            int t = __shfl_up(s, off, 64);
            if (lane >= off) s += t;
        }
        if (i < nb) partials[i] = carry + s - v;
        carry += __shfl(s, 63, 64);
    }
}

// Pass C: block-local exclusive scan + block offset -> row_start/cursor; fused dinv.
__global__ void scan_emit(const int* __restrict__ deg, const int* __restrict__ partials,
                          int* __restrict__ row_start, int* __restrict__ cursor,
                          float* __restrict__ dinv, int N) {
    __shared__ int wsum_s[NWAVES];
    __shared__ int wexcl_s[NWAVES];
    int idx = blockIdx.x * SCAN_CHUNK + threadIdx.x * SCAN_K;
    int v[SCAN_K];
    int lsum = 0;
#pragma unroll
    for (int k = 0; k < SCAN_K; ++k) {
        v[k] = (idx + k < N) ? deg[idx + k] : 0;
        lsum += v[k];
    }
    int lane = threadIdx.x & 63, wid = threadIdx.x >> 6;
    int ls = lsum;
#pragma unroll
    for (int off = 1; off < 64; off <<= 1) {
        int t = __shfl_up(ls, off, 64);
        if (lane >= off) ls += t;
    }
    if (lane == 63) wsum_s[wid] = ls;
    __syncthreads();
    if (threadIdx.x == 0) {
        int run = 0;
#pragma unroll
        for (int w = 0; w < NWAVES; ++w) { wexcl_s[w] = run; run += wsum_s[w]; }
    }
    __syncthreads();
    int run = partials[blockIdx.x] + wexcl_s[wid] + (ls - lsum);
#pragma unroll
    for (int k = 0; k < SCAN_K; ++k) {
        int i = idx + k;
        if (i < N) {
            row_start[i] = run;
            cursor[i] = run;
            dinv[i] = (v[k] > 0) ? rsqrtf((float)v[k]) : 0.f;
        }
        run += v[k];
    }
}

__global__ void build_csr(const int* __restrict__ row, const int* __restrict__ col,
                          int* __restrict__ cursor, int* __restrict__ csr_col, int E) {
    int e = blockIdx.x * blockDim.x + threadIdx.x;
    if (e >= E) return;
    int r = row[e];
    int pos = atomicAdd(&cursor[r], 1);
    csr_col[pos] = col[e];
}

// One wave per node. lane = (g:2 | q:4); g = neighbor slot (4 gather chains in
// flight), q = float4 feature index. Cross-group __shfl_xor reduction at end.
__global__ void aggregate(const float4* __restrict__ x4,
                          const int* __restrict__ row_start,
                          const int* __restrict__ row_end,
                          const int* __restrict__ csr_col,
                          const float* __restrict__ dinv,
                          float4* __restrict__ out4, int N) {
    int node = blockIdx.x * (blockDim.x >> 6) + (threadIdx.x >> 6);
    if (node >= N) return;
    int lane = threadIdx.x & 63;
    int g = lane >> 4;     // 0..3: neighbor slot
    int q = lane & 15;     // 0..15: float4 within feature row
    int s = row_start[node];
    int e = row_end[node];
    float4 acc = {0.f, 0.f, 0.f, 0.f};
    for (int i = s + g; i < e; i += 4) {
        int c = csr_col[i];
        float w = dinv[c];
        float4 v = x4[(size_t)c * 16 + q];
        acc.x += w * v.x; acc.y += w * v.y; acc.z += w * v.z; acc.w += w * v.w;
    }
    // reduce across the 4 neighbor slots (lanes differing in bits 4..5)
#pragma unroll
    for (int off = 16; off < 64; off <<= 1) {
        acc.x += __shfl_xor(acc.x, off, 64);
        acc.y += __shfl_xor(acc.y, off, 64);
        acc.z += __shfl_xor(acc.z, off, 64);
        acc.w += __shfl_xor(acc.w, off, 64);
    }
    float w0 = dinv[node];
    if (g == 0) {
        float4 r = make_float4(acc.x * w0, acc.y * w0, acc.z * w0, acc.w * w0);
        out4[(size_t)node * 32 + 16 + q] = r;
    } else if (g == 1) {
        out4[(size_t)node * 32 + q] = x4[(size_t)node * 16 + q];
    }
}

extern "C" void kernel_launch(void* const* d_in, const int* in_sizes, int n_in,
                              void* d_out, int out_size, void* d_ws, size_t ws_size,
                              hipStream_t stream) {
    const float* x = (const float*)d_in[0];
    const int* ei = (const int*)d_in[1];

    const int N = in_sizes[0] / 64;   // 100000
    const int E = in_sizes[1] / 2;    // 1600000
    const int* row = ei;
    const int* col = ei + E;

    int nscan_blocks = (N + SCAN_CHUNK - 1) / SCAN_CHUNK;  // 49

    // workspace layout
    char* ws = (char*)d_ws;
    int* deg       = (int*)ws;   ws += (size_t)N * sizeof(int);
    int* row_start = (int*)ws;   ws += (size_t)N * sizeof(int);
    int* cursor    = (int*)ws;   ws += (size_t)N * sizeof(int);
    float* dinv    = (float*)ws; ws += (size_t)N * sizeof(float);
    int* partials  = (int*)ws;   ws += (size_t)((nscan_blocks + 63) & ~63) * sizeof(int);
    int* csr_col   = (int*)ws;   // E ints

    float* out = (float*)d_out;

    hipMemsetAsync(deg, 0, (size_t)N * sizeof(int), stream);

    deg_kernel<<<(E + THREADS - 1) / THREADS, THREADS, 0, stream>>>(row, deg, E);

    scan_sums<<<nscan_blocks, THREADS, 0, stream>>>(deg, partials, N);
    scan_partials<<<1, 64, 0, stream>>>(partials, nscan_blocks);
    scan_emit<<<nscan_blocks, THREADS, 0, stream>>>(deg, partials, row_start, cursor, dinv, N);

    build_csr<<<(E + THREADS - 1) / THREADS, THREADS, 0, stream>>>(row, col, cursor, csr_col, E);

    int nodes_per_block = THREADS / 64;
    int blocks = (N + nodes_per_block - 1) / nodes_per_block;
    aggregate<<<blocks, THREADS, 0, stream>>>((const float4*)x, row_start, cursor, csr_col,
                                              dinv, (float4*)out, N);
}

// Round 4
// 206.229 us; speedup vs baseline: 7.0923x; 1.3747x over previous
//
#include <hip/hip_runtime.h>

#define THREADS 256

// One atomic pass builds per-node linked lists over edges:
//   next[e] = old head of row[e]; head[row[e]] = e.
// next[] store is coalesced (indexed by e); only head[] sees random atomics.
__global__ void build_lists(const int* __restrict__ row, int* __restrict__ head,
                            int* __restrict__ next, int E) {
    int e = blockIdx.x * blockDim.x + threadIdx.x;
    if (e >= E) return;
    next[e] = atomicExch(&head[row[e]], e);
}

// Degree = chain length; dinv = rsqrt(deg) or 0. One thread per node.
__global__ void count_dinv(const int* __restrict__ head, const int* __restrict__ next,
                           float* __restrict__ dinv, int N) {
    int i = blockIdx.x * blockDim.x + threadIdx.x;
    if (i >= N) return;
    int e = head[i];
    int cnt = 0;
    while (e >= 0) { ++cnt; e = next[e]; }
    dinv[i] = (cnt > 0) ? rsqrtf((float)cnt) : 0.f;
}

// 4 nodes per wave: lane = (g:2 | q:4). Group g walks node's chain (serial),
// its 16 lanes each hold one float4 of the 64-float feature row.
// out[node, :64] = x[node]; out[node, 64:] = dinv[node] * sum dinv[c]*x[c].
__global__ void aggregate(const float4* __restrict__ x4,
                          const int* __restrict__ head,
                          const int* __restrict__ next,
                          const int* __restrict__ col,
                          const float* __restrict__ dinv,
                          float4* __restrict__ out4, int N) {
    int wid = threadIdx.x >> 6;
    int lane = threadIdx.x & 63;
    int g = lane >> 4;       // 0..3: node slot within wave
    int q = lane & 15;       // 0..15: float4 within feature row
    int node = (blockIdx.x * (blockDim.x >> 6) + wid) * 4 + g;
    if (node >= N) return;

    float4 acc = {0.f, 0.f, 0.f, 0.f};
    int e = head[node];
    while (e >= 0) {
        int en = next[e];            // issue chase load first
        int c = col[e];
        float w = dinv[c];
        float4 v = x4[(size_t)c * 16 + q];
        acc.x += w * v.x; acc.y += w * v.y; acc.z += w * v.z; acc.w += w * v.w;
        e = en;
    }
    float w0 = dinv[node];
    out4[(size_t)node * 32 + q] = x4[(size_t)node * 16 + q];
    float4 r = make_float4(acc.x * w0, acc.y * w0, acc.z * w0, acc.w * w0);
    out4[(size_t)node * 32 + 16 + q] = r;
}

extern "C" void kernel_launch(void* const* d_in, const int* in_sizes, int n_in,
                              void* d_out, int out_size, void* d_ws, size_t ws_size,
                              hipStream_t stream) {
    const float* x = (const float*)d_in[0];
    const int* ei = (const int*)d_in[1];

    const int N = in_sizes[0] / 64;   // 100000
    const int E = in_sizes[1] / 2;    // 1600000
    const int* row = ei;
    const int* col = ei + E;

    // workspace: head[N], dinv[N], next[E]
    char* ws = (char*)d_ws;
    int* head   = (int*)ws;   ws += (size_t)N * sizeof(int);
    float* dinv = (float*)ws; ws += (size_t)N * sizeof(float);
    int* next   = (int*)ws;   // E ints

    float* out = (float*)d_out;

    // head = -1 everywhere
    hipMemsetAsync(head, 0xFF, (size_t)N * sizeof(int), stream);

    build_lists<<<(E + THREADS - 1) / THREADS, THREADS, 0, stream>>>(row, head, next, E);

    count_dinv<<<(N + THREADS - 1) / THREADS, THREADS, 0, stream>>>(head, next, dinv, N);

    // 4 waves/block * 4 nodes/wave = 16 nodes per block
    int nodes_per_block = (THREADS / 64) * 4;
    int blocks = (N + nodes_per_block - 1) / nodes_per_block;
    aggregate<<<blocks, THREADS, 0, stream>>>((const float4*)x, head, next, col, dinv,
                                              (float4*)out, N);
}

// Round 5
// 177.890 us; speedup vs baseline: 8.2221x; 1.1593x over previous
//
#include <hip/hip_runtime.h>

#define THREADS 256

// Per-node linked lists over edges: next[e] = old head of row[e].
// next[] store is coalesced; only head[] (400 KB, L2-resident) sees atomics.
__global__ void build_lists(const int* __restrict__ row, int* __restrict__ head,
                            int* __restrict__ next, int E) {
    int e = blockIdx.x * blockDim.x + threadIdx.x;
    if (e >= E) return;
    next[e] = atomicExch(&head[row[e]], e);
}

// Degree = chain length; dinv = rsqrt(deg) or 0.
__global__ void count_dinv(const int* __restrict__ head, const int* __restrict__ next,
                           float* __restrict__ dinv, int N) {
    int i = blockIdx.x * blockDim.x + threadIdx.x;
    if (i >= N) return;
    int e = head[i];
    int cnt = 0;
    while (e >= 0) { ++cnt; e = next[e]; }
    dinv[i] = (cnt > 0) ? rsqrtf((float)cnt) : 0.f;
}

__device__ inline unsigned short bf16_rne(float f) {
    union { float f; unsigned u; } t; t.f = f;
    unsigned u = t.u;
    u += 0x7FFFu + ((u >> 16) & 1u);   // round to nearest even
    return (unsigned short)(u >> 16);
}

// y[n][d] = bf16(dinv[n]*x[n][d]); also out[n][0:64] = x[n].
// One thread per float4 chunk (N*16 threads).
__global__ void scale_copy(const float4* __restrict__ x4, const float* __restrict__ dinv,
                           float4* __restrict__ out4, ushort4* __restrict__ y4, int total) {
    int i = blockIdx.x * blockDim.x + threadIdx.x;
    if (i >= total) return;
    int n = i >> 4, q = i & 15;
    float4 v = x4[i];
    float w = dinv[n];
    out4[(size_t)n * 32 + q] = v;
    ushort4 h;
    h.x = bf16_rne(v.x * w);
    h.y = bf16_rne(v.y * w);
    h.z = bf16_rne(v.z * w);
    h.w = bf16_rne(v.w * w);
    y4[i] = h;
}

// 8 nodes per wave: lane = (g:3 | q:3). Group g walks node's chain; each of its
// 8 lanes gathers one 16 B chunk (8 bf16 features) of y[col] and accumulates f32.
// out[node, 64+8q .. 64+8q+7] = dinv[node] * acc.
__global__ void aggregate(const uint4* __restrict__ y16,
                          const int* __restrict__ head,
                          const int* __restrict__ next,
                          const int* __restrict__ col,
                          const float* __restrict__ dinv,
                          float4* __restrict__ out4, int N) {
    int wid = threadIdx.x >> 6;
    int lane = threadIdx.x & 63;
    int g = lane >> 3;      // 0..7: node slot within wave
    int q = lane & 7;       // 0..7: 16B chunk of the 128B bf16 feature row
    int node = (blockIdx.x * (blockDim.x >> 6) + wid) * 8 + g;
    if (node >= N) return;

    float a0 = 0.f, a1 = 0.f, a2 = 0.f, a3 = 0.f, a4 = 0.f, a5 = 0.f, a6 = 0.f, a7 = 0.f;
    int e = head[node];
    while (e >= 0) {
        int en = next[e];            // dependent chase load, issue first
        int c = col[e];
        uint4 v = y16[(size_t)c * 8 + q];
        a0 += __uint_as_float(v.x << 16);
        a1 += __uint_as_float(v.x & 0xFFFF0000u);
        a2 += __uint_as_float(v.y << 16);
        a3 += __uint_as_float(v.y & 0xFFFF0000u);
        a4 += __uint_as_float(v.z << 16);
        a5 += __uint_as_float(v.z & 0xFFFF0000u);
        a6 += __uint_as_float(v.w << 16);
        a7 += __uint_as_float(v.w & 0xFFFF0000u);
        e = en;
    }
    float w0 = dinv[node];
    float4 r0 = make_float4(a0 * w0, a1 * w0, a2 * w0, a3 * w0);
    float4 r1 = make_float4(a4 * w0, a5 * w0, a6 * w0, a7 * w0);
    size_t base = (size_t)node * 32 + 16 + q * 2;
    out4[base] = r0;
    out4[base + 1] = r1;
}

extern "C" void kernel_launch(void* const* d_in, const int* in_sizes, int n_in,
                              void* d_out, int out_size, void* d_ws, size_t ws_size,
                              hipStream_t stream) {
    const float* x = (const float*)d_in[0];
    const int* ei = (const int*)d_in[1];

    const int N = in_sizes[0] / 64;   // 100000
    const int E = in_sizes[1] / 2;    // 1600000
    const int* row = ei;
    const int* col = ei + E;

    // workspace: head[N] int, dinv[N] f32, next[E] int, y[N][64] bf16  (~20 MB)
    char* ws = (char*)d_ws;
    int* head    = (int*)ws;     ws += (size_t)N * sizeof(int);
    float* dinv  = (float*)ws;   ws += (size_t)N * sizeof(float);
    int* next    = (int*)ws;     ws += (size_t)E * sizeof(int);
    ushort4* y4  = (ushort4*)ws; // N*16 ushort4 = N*128 B

    float* out = (float*)d_out;

    hipMemsetAsync(head, 0xFF, (size_t)N * sizeof(int), stream);

    build_lists<<<(E + THREADS - 1) / THREADS, THREADS, 0, stream>>>(row, head, next, E);

    count_dinv<<<(N + THREADS - 1) / THREADS, THREADS, 0, stream>>>(head, next, dinv, N);

    int total = N * 16;
    scale_copy<<<(total + THREADS - 1) / THREADS, THREADS, 0, stream>>>(
        (const float4*)x, dinv, (float4*)out, y4, total);

    // 4 waves/block * 8 nodes/wave = 32 nodes per block
    int nodes_per_block = (THREADS / 64) * 8;
    int blocks = (N + nodes_per_block - 1) / nodes_per_block;
    aggregate<<<blocks, THREADS, 0, stream>>>((const uint4*)y4, head, next, col, dinv,
                                              (float4*)out, N);
}

// Round 6
// 104.626 us; speedup vs baseline: 13.9796x; 1.7002x over previous
//
#include <hip/hip_runtime.h>

#define THREADS 256
#define EB 256                 // number of edge blocks for bucketing
#define BSHIFT 7
#define BROWS (1 << BSHIFT)    // 128 rows per bucket
#define MAXNB 1024             // static LDS bound: supports N up to 131072

// P1: per-edge-block histogram over row buckets (LDS atomics only).
__global__ void bucket_hist(const int* __restrict__ row, int* __restrict__ h,
                            int E, int per, int NB) {
    __shared__ int lds[MAXNB];
    for (int k = threadIdx.x; k < NB; k += blockDim.x) lds[k] = 0;
    __syncthreads();
    int lo = blockIdx.x * per;
    int hi = min(E, lo + per);
    for (int i = lo + threadIdx.x; i < hi; i += blockDim.x)
        atomicAdd(&lds[row[i] >> BSHIFT], 1);
    __syncthreads();
    int* hb = h + (size_t)blockIdx.x * NB;
    for (int k = threadIdx.x; k < NB; k += blockDim.x) hb[k] = lds[k];
}

// S1: exclusive scan down each bucket column of h (one block per bucket).
__global__ void scan_cols(int* __restrict__ h, int* __restrict__ totals, int NB) {
    int k = blockIdx.x;
    int lane = threadIdx.x;  // 64 threads
    int carry = 0;
#pragma unroll
    for (int base = 0; base < EB; base += 64) {
        int idx = (base + lane) * NB + k;
        int v = h[idx];
        int s = v;
#pragma unroll
        for (int off = 1; off < 64; off <<= 1) {
            int t = __shfl_up(s, off, 64);
            if (lane >= off) s += t;
        }
        h[idx] = carry + s - v;
        carry += __shfl(s, 63, 64);
    }
    if (lane == 0) totals[k] = carry;
}

// S2: exclusive scan of bucket totals -> bucket starts; sentinels.
__global__ void scan_totals(const int* __restrict__ totals, int* __restrict__ bstart,
                            int* __restrict__ row_start, int NB, int N, int E) {
    int lane = threadIdx.x;  // 64 threads
    int carry = 0;
    for (int base = 0; base < NB; base += 64) {
        int i = base + lane;
        int v = (i < NB) ? totals[i] : 0;
        int s = v;
#pragma unroll
        for (int off = 1; off < 64; off <<= 1) {
            int t = __shfl_up(s, off, 64);
            if (lane >= off) s += t;
        }
        if (i < NB) bstart[i] = carry + s - v;
        carry += __shfl(s, 63, 64);
    }
    if (lane == 0) { bstart[NB] = E; row_start[N] = E; }
}

// P1b: scatter (row,col) into bucket-sorted order at deterministic positions.
__global__ void bucket_scatter(const int* __restrict__ row, const int* __restrict__ col,
                               const int* __restrict__ h, const int* __restrict__ bstart,
                               unsigned long long* __restrict__ sorted,
                               int E, int per, int NB) {
    __shared__ int cur[MAXNB];
    const int* hb = h + (size_t)blockIdx.x * NB;
    for (int k = threadIdx.x; k < NB; k += blockDim.x) cur[k] = bstart[k] + hb[k];
    __syncthreads();
    int lo = blockIdx.x * per;
    int hi = min(E, lo + per);
    for (int i = lo + threadIdx.x; i < hi; i += blockDim.x) {
        int r = row[i];
        int pos = atomicAdd(&cur[r >> BSHIFT], 1);
        sorted[pos] = ((unsigned long long)(unsigned)r << 32) | (unsigned)col[i];
    }
}

// P2: one block per bucket: per-row counts -> row_start + dinv, then group
// cols by row into csr_col (all LDS atomics, coalesced output window).
__global__ void bucket_group(const unsigned long long* __restrict__ sorted,
                             const int* __restrict__ bstart,
                             int* __restrict__ csr_col, int* __restrict__ row_start,
                             float* __restrict__ dinv, int N, int NB) {
    __shared__ int hist[BROWS];
    __shared__ int cur[BROWS];
    int k = blockIdx.x;
    int base = bstart[k];
    int cnt = bstart[k + 1] - base;
    for (int r = threadIdx.x; r < BROWS; r += blockDim.x) hist[r] = 0;
    __syncthreads();
    for (int i = threadIdx.x; i < cnt; i += blockDim.x) {
        int r = (int)(sorted[base + i] >> 32) & (BROWS - 1);
        atomicAdd(&hist[r], 1);
    }
    __syncthreads();
    if (threadIdx.x < 64) {
        int lane = threadIdx.x;
        int carry = 0;
#pragma unroll
        for (int b2 = 0; b2 < BROWS; b2 += 64) {
            int v = hist[b2 + lane];
            int s = v;
#pragma unroll
            for (int off = 1; off < 64; off <<= 1) {
                int t = __shfl_up(s, off, 64);
                if (lane >= off) s += t;
            }
            int pref = carry + s - v;
            cur[b2 + lane] = pref;
            int node = (k << BSHIFT) + b2 + lane;
            if (node < N) {
                row_start[node] = base + pref;
                dinv[node] = (v > 0) ? rsqrtf((float)v) : 0.f;
            }
            carry += __shfl(s, 63, 64);
        }
    }
    __syncthreads();
    for (int i = threadIdx.x; i < cnt; i += blockDim.x) {
        unsigned long long rc = sorted[base + i];
        int r = (int)(rc >> 32) & (BROWS - 1);
        int pos = base + atomicAdd(&cur[r], 1);
        csr_col[pos] = (int)(unsigned)rc;
    }
}

__device__ inline unsigned short bf16_rne(float f) {
    union { float f; unsigned u; } t; t.f = f;
    unsigned u = t.u;
    u += 0x7FFFu + ((u >> 16) & 1u);   // round to nearest even
    return (unsigned short)(u >> 16);
}

// y[n][d] = bf16(dinv[n]*x[n][d]); also out[n][0:64] = x[n].
__global__ void scale_copy(const float4* __restrict__ x4, const float* __restrict__ dinv,
                           float4* __restrict__ out4, ushort4* __restrict__ y4, int total) {
    int i = blockIdx.x * blockDim.x + threadIdx.x;
    if (i >= total) return;
    int n = i >> 4, q = i & 15;
    float4 v = x4[i];
    float w = dinv[n];
    out4[(size_t)n * 32 + q] = v;
    ushort4 h;
    h.x = bf16_rne(v.x * w);
    h.y = bf16_rne(v.y * w);
    h.z = bf16_rne(v.z * w);
    h.w = bf16_rne(v.w * w);
    y4[i] = h;
}

// 8 nodes per wave: lane = (g:3 | q:3). Group g iterates its node's CSR range
// (independent 16 B gathers, 2x unrolled); q = 16 B chunk of the bf16 row.
__global__ void aggregate(const uint4* __restrict__ y16,
                          const int* __restrict__ row_start,
                          const int* __restrict__ csr_col,
                          const float* __restrict__ dinv,
                          float4* __restrict__ out4, int N) {
    int wid = threadIdx.x >> 6;
    int lane = threadIdx.x & 63;
    int g = lane >> 3;      // 0..7: node slot within wave
    int q = lane & 7;       // 0..7: 16B chunk of 128B bf16 feature row
    int node = (blockIdx.x * (blockDim.x >> 6) + wid) * 8 + g;
    if (node >= N) return;

    int s = row_start[node];
    int e = row_start[node + 1];
    float a0 = 0.f, a1 = 0.f, a2 = 0.f, a3 = 0.f, a4 = 0.f, a5 = 0.f, a6 = 0.f, a7 = 0.f;
    int i = s;
    for (; i + 1 < e; i += 2) {
        int c0 = csr_col[i];
        int c1 = csr_col[i + 1];
        uint4 v0 = y16[(size_t)c0 * 8 + q];
        uint4 v1 = y16[(size_t)c1 * 8 + q];
        a0 += __uint_as_float(v0.x << 16);
        a1 += __uint_as_float(v0.x & 0xFFFF0000u);
        a2 += __uint_as_float(v0.y << 16);
        a3 += __uint_as_float(v0.y & 0xFFFF0000u);
        a4 += __uint_as_float(v0.z << 16);
        a5 += __uint_as_float(v0.z & 0xFFFF0000u);
        a6 += __uint_as_float(v0.w << 16);
        a7 += __uint_as_float(v0.w & 0xFFFF0000u);
        a0 += __uint_as_float(v1.x << 16);
        a1 += __uint_as_float(v1.x & 0xFFFF0000u);
        a2 += __uint_as_float(v1.y << 16);
        a3 += __uint_as_float(v1.y & 0xFFFF0000u);
        a4 += __uint_as_float(v1.z << 16);
        a5 += __uint_as_float(v1.z & 0xFFFF0000u);
        a6 += __uint_as_float(v1.w << 16);
        a7 += __uint_as_float(v1.w & 0xFFFF0000u);
    }
    if (i < e) {
        int c0 = csr_col[i];
        uint4 v0 = y16[(size_t)c0 * 8 + q];
        a0 += __uint_as_float(v0.x << 16);
        a1 += __uint_as_float(v0.x & 0xFFFF0000u);
        a2 += __uint_as_float(v0.y << 16);
        a3 += __uint_as_float(v0.y & 0xFFFF0000u);
        a4 += __uint_as_float(v0.z << 16);
        a5 += __uint_as_float(v0.z & 0xFFFF0000u);
        a6 += __uint_as_float(v0.w << 16);
        a7 += __uint_as_float(v0.w & 0xFFFF0000u);
    }
    float w0 = dinv[node];
    float4 r0 = make_float4(a0 * w0, a1 * w0, a2 * w0, a3 * w0);
    float4 r1 = make_float4(a4 * w0, a5 * w0, a6 * w0, a7 * w0);
    size_t obase = (size_t)node * 32 + 16 + q * 2;
    out4[obase] = r0;
    out4[obase + 1] = r1;
}

extern "C" void kernel_launch(void* const* d_in, const int* in_sizes, int n_in,
                              void* d_out, int out_size, void* d_ws, size_t ws_size,
                              hipStream_t stream) {
    const float* x = (const float*)d_in[0];
    const int* ei = (const int*)d_in[1];

    const int N = in_sizes[0] / 64;   // 100000
    const int E = in_sizes[1] / 2;    // 1600000
    const int* row = ei;
    const int* col = ei + E;

    const int NB = (N + BROWS - 1) >> BSHIFT;   // 782 buckets
    const int per = (E + EB - 1) / EB;          // edges per bucket-block

    // workspace layout (sorted first for 8B alignment; y4 overlays sorted
    // after bucket_group has consumed it)
    char* ws = (char*)d_ws;
    unsigned long long* sorted = (unsigned long long*)ws; ws += (size_t)E * 8;
    int* h         = (int*)ws;   ws += (size_t)EB * NB * sizeof(int);
    int* totals    = (int*)ws;   ws += (size_t)NB * sizeof(int);
    int* bstart    = (int*)ws;   ws += (size_t)(NB + 1) * sizeof(int);
    int* row_start = (int*)ws;   ws += (size_t)(N + 1) * sizeof(int);
    float* dinv    = (float*)ws; ws += (size_t)N * sizeof(float);
    int* csr_col   = (int*)ws;   // E ints
    ushort4* y4 = (ushort4*)sorted;

    float* out = (float*)d_out;

    bucket_hist<<<EB, THREADS, 0, stream>>>(row, h, E, per, NB);
    scan_cols<<<NB, 64, 0, stream>>>(h, totals, NB);
    scan_totals<<<1, 64, 0, stream>>>(totals, bstart, row_start, NB, N, E);
    bucket_scatter<<<EB, THREADS, 0, stream>>>(row, col, h, bstart, sorted, E, per, NB);
    bucket_group<<<NB, THREADS, 0, stream>>>(sorted, bstart, csr_col, row_start, dinv, N, NB);

    int total = N * 16;
    scale_copy<<<(total + THREADS - 1) / THREADS, THREADS, 0, stream>>>(
        (const float4*)x, dinv, (float4*)out, y4, total);

    int nodes_per_block = (THREADS / 64) * 8;   // 32
    int blocks = (N + nodes_per_block - 1) / nodes_per_block;
    aggregate<<<blocks, THREADS, 0, stream>>>((const uint4*)y4, row_start, csr_col,
                                              dinv, (float4*)out, N);
}